// Round 5
// baseline (241.589 us; speedup 1.0000x reference)
//
#include <hip/hip_runtime.h>
#include <hip/hip_bf16.h>
#include <stdint.h>

// ModulatedConv2d: N=16, IC=OC=256, H=W=64, K=3, STYLE=512. fp32 in/out.
// out = demod[n,oc] * conv2d( x * (1+s)[n,ic], weight )   (StyleGAN2 identity)
// R5: xs intermediate eliminated — modulate+NCHW->[sp][ic] transpose fused into
// k_conv's A-slab staging (per-ic-chunk slab reused across all 9 taps).
// Block = 128 sp x 256 oc (8 waves); demod computed in-block from wsq+scale.

#define NB  16
#define IC  256
#define OC  256
#define HW  64
#define SD  512
#define SPATIAL 4096

typedef __hip_bfloat16 bf16;
typedef __bf16 bf16x8 __attribute__((ext_vector_type(8)));
typedef float  f32x4  __attribute__((ext_vector_type(4)));
typedef uint32_t u32a3 __attribute__((address_space(3)));
typedef const uint32_t u32a1 __attribute__((address_space(1)));

static __device__ __forceinline__ unsigned short f2bu(float f) {
    bf16 h = __float2bfloat16(f);
    union { bf16 b; unsigned short u; } c; c.b = h; return c.u;
}
static __device__ __forceinline__ void gll16(const void* g, void* l) {
    __builtin_amdgcn_global_load_lds((u32a1*)g, (u32a3*)l, 16, 0, 0);
}

// --- P1: fused prep. blocks [0,256): wt2+wsq; [256,1280): scale -------------
__global__ __launch_bounds__(256)
void k_prep1(const float* __restrict__ weight, const float* __restrict__ style,
             const float* __restrict__ mod_w, const float* __restrict__ mod_b,
             float* __restrict__ wsq, bf16* __restrict__ wt2,
             float* __restrict__ scale) {
    int b = blockIdx.x, t = threadIdx.x;
    if (b < 256) {
        // wsq[oc,ic] = sum_r w^2 ; wt2[r][oc][ic] = bf16(w)
        int tid = b * 256 + t;
        const float* wp = weight + (size_t)tid * 9;
        float v[9], s = 0.f;
        #pragma unroll
        for (int r = 0; r < 9; ++r) { v[r] = wp[r]; s += v[r] * v[r]; }
        wsq[tid] = s;
        #pragma unroll
        for (int r = 0; r < 9; ++r) wt2[(r << 16) + tid] = __float2bfloat16(v[r]);
    } else {
        // scale[n,ic] = 1 + style[n,:].mod_w[ic,:] + mod_b[ic]; one wave/output
        int lane = t & 63;
        int w = (b - 256) * 4 + (t >> 6);       // 0..4095 = n*256+ic
        int n = w >> 8, ic = w & 255;
        const float4* mw4 = (const float4*)mod_w + (size_t)ic * 128 + lane * 2;
        const float4* st4 = (const float4*)style + (size_t)n * 128 + lane * 2;
        float4 a0 = mw4[0], a1 = mw4[1], s0 = st4[0], s1 = st4[1];
        float acc = a0.x*s0.x + a0.y*s0.y + a0.z*s0.z + a0.w*s0.w
                  + a1.x*s1.x + a1.y*s1.y + a1.z*s1.z + a1.w*s1.w;
        #pragma unroll
        for (int off = 32; off > 0; off >>= 1) acc += __shfl_down(acc, off);
        if (lane == 0) scale[w] = acc + mod_b[ic] + 1.0f;
    }
}

// --- K: fused modulate + implicit-GEMM conv + demod -------------------------
// grid 512: block -> (n, 2-row spatial tile), 128 sp x 256 oc, 512 threads.
__global__ __launch_bounds__(512, 4)
void k_conv(const float* __restrict__ x, const bf16* __restrict__ wt2,
            const float* __restrict__ scale, const float* __restrict__ wsq,
            float* __restrict__ out) {
    __shared__ uint32_t As[4 * 66 * 32];        // slab [row0..3][col0..65][64 ic] 33 KB
    __shared__ uint32_t Bs[256 * 32];           // B-tile [256 oc][64 ic] 32 KB
    __shared__ float sc_s[256];                 // scale row for this n
    __shared__ float dm_s[256];                 // demod row for this n

    int t = threadIdx.x, l = t & 63, w = t >> 6;   // 8 waves
    int wm = w & 1, wn = w >> 1;                // sp-half, oc-quarter
    int bid = blockIdx.x;
    int work = ((bid & 7) << 6) | (bid >> 3);   // XCD-contiguous
    int n = work >> 5, st = work & 31;
    int y0 = st << 1;                           // first image row of tile
    int sp_base = st << 7;

    // ---- prologue: scale row + per-(n,oc) demod ----
    if (t < 256) {
        sc_s[t] = scale[n * IC + t];
        const float4* wq4 = (const float4*)(wsq + (size_t)t * IC);
        const float4* sl4 = (const float4*)(scale + (size_t)n * IC);
        float acc = 0.f;
        #pragma unroll 4
        for (int i = 0; i < 64; ++i) {
            float4 q = wq4[i], s = sl4[i];
            acc += q.x*s.x*s.x + q.y*s.y*s.y + q.z*s.z*s.z + q.w*s.w*s.w;
        }
        dm_s[t] = rsqrtf(acc + 1e-8f);
        // zero the pad columns x'=0 and x'=65 (ic-independent, once)
        int ypz = t >> 6, cz = (t >> 5) & 1, icpz = t & 31;
        int xz = cz ? 65 : 0;
        int segp = (icpz >> 2) ^ (((xz >> 2) ^ xz) & 7);
        As[(ypz * 66 + xz) * 32 + segp * 4 + (icpz & 3)] = 0u;
    }

    // B staging geometry (proven R4): wave w stages oc rows [w*32,(w+1)*32)
    int lrow = l >> 3, lseg = (l & 7) ^ lrow;
    const bf16* gB0 = wt2 + (size_t)(w * 32 + lrow) * IC + lseg * 8;
    char* Bb = (char*)Bs + w * 4096;

    f32x4 acc[4][4];
    #pragma unroll
    for (int i = 0; i < 4; ++i)
        #pragma unroll
        for (int j = 0; j < 4; ++j) acc[i][j] = (f32x4){0.f, 0.f, 0.f, 0.f};

    int q0 = l >> 4, l15 = l & 15, l7 = l & 7;
    const float4* x4 = (const float4*)x;

    for (int c = 0; c < 4; ++c) {
        int ic0 = c << 6;
        __syncthreads();                        // prior reads of As/Bs done
        // ---- stage A slab: x[n][ic0..ic0+63][y0-1..y0+2][0..63] -> bf16*scale
        #pragma unroll
        for (int j = 0; j < 4; ++j) {
            int u = j * 512 + t;
            int xq = u & 15, yp = (u >> 4) & 3, icp = u >> 6;   // icp 0..31
            int ic = ic0 + (icp << 1);
            int y = y0 + yp - 1;
            int vok = ((unsigned)y < 64u) ? 1 : 0;
            size_t bx = ((size_t)((n * IC + ic) * 64 + (vok ? y : 0))) * 16 + xq;
            float4 va = x4[bx], vb = x4[bx + 1024];
            float sa = vok ? sc_s[ic] : 0.f;
            float sb = vok ? sc_s[ic + 1] : 0.f;
            float av[4] = {va.x, va.y, va.z, va.w};
            float bv[4] = {vb.x, vb.y, vb.z, vb.w};
            int xb = (xq << 2) + 1;
            #pragma unroll
            for (int e = 0; e < 4; ++e) {
                int xc = xb + e;
                int segp = (icp >> 2) ^ (((xc >> 2) ^ xc) & 7);
                As[(yp * 66 + xc) * 32 + segp * 4 + (icp & 3)] =
                    (uint32_t)f2bu(av[e] * sa) | ((uint32_t)f2bu(bv[e] * sb) << 16);
            }
        }
        for (int r = 0; r < 9; ++r) {
            int ky = r / 3, kx = r - ky * 3;
            int boff = (r << 16) + ic0;         // wave-uniform
            __syncthreads();                    // slab ready (r=0) / prev B reads done
            #pragma unroll
            for (int i = 0; i < 4; ++i)
                gll16(gB0 + boff + i * 2048, Bb + i * 1024);
            __syncthreads();                    // B ready
            #pragma unroll
            for (int kk = 0; kk < 2; ++kk) {
                int g = (kk << 2) + q0;         // global k-seg 0..7
                bf16x8 af[4], bfr[4];
                #pragma unroll
                for (int mi = 0; mi < 4; ++mi) {
                    int col = mi * 16 + l15 + kx;
                    int pos = (wm + ky) * 66 + col;
                    int segp = g ^ (((col >> 2) ^ col) & 7);
                    af[mi] = *reinterpret_cast<const bf16x8*>(
                        (const unsigned short*)As + pos * 64 + segp * 8);
                }
                #pragma unroll
                for (int ni = 0; ni < 4; ++ni) {
                    int rB = wn * 64 + ni * 16 + l15;
                    bfr[ni] = *reinterpret_cast<const bf16x8*>(
                        (const unsigned short*)Bs + rB * 64 + ((g ^ l7) << 3));
                }
                #pragma unroll
                for (int mi = 0; mi < 4; ++mi)
                    #pragma unroll
                    for (int ni = 0; ni < 4; ++ni)
                        acc[mi][ni] = __builtin_amdgcn_mfma_f32_16x16x32_bf16(
                            af[mi], bfr[ni], acc[mi][ni], 0, 0, 0);
            }
        }
    }

    // epilogue: D[row=(l>>4)*4+v][col=l&15]; rows = consecutive sp -> 16B stores
    int orow = (l >> 4) << 2;
    #pragma unroll
    for (int ni = 0; ni < 4; ++ni) {
        int oc = wn * 64 + ni * 16 + l15;
        float d = dm_s[oc];
        size_t ob = ((size_t)(n * OC + oc)) * SPATIAL + sp_base + wm * 64 + orow;
        #pragma unroll
        for (int mi = 0; mi < 4; ++mi) {
            f32x4 a = acc[mi][ni];
            f32x4 o = { a[0] * d, a[1] * d, a[2] * d, a[3] * d };
            *reinterpret_cast<f32x4*>(out + ob + mi * 16) = o;
        }
    }
}

extern "C" void kernel_launch(void* const* d_in, const int* in_sizes, int n_in,
                              void* d_out, int out_size, void* d_ws, size_t ws_size,
                              hipStream_t stream) {
    const float* x      = (const float*)d_in[0];
    const float* style  = (const float*)d_in[1];
    const float* weight = (const float*)d_in[2];
    const float* mod_w  = (const float*)d_in[3];
    const float* mod_b  = (const float*)d_in[4];
    float* out = (float*)d_out;

    char* ws = (char*)d_ws;                  // ~1.5 MB used
    float* scale = (float*)(ws + 0);         // 16 KB
    float* wsq   = (float*)(ws + 16384);     // 256 KB
    bf16*  wt2   = (bf16*)(ws + 278528);     // 1.18 MB [r][oc][ic]

    k_prep1<<<1280, 256, 0, stream>>>(weight, style, mod_w, mod_b, wsq, wt2, scale);
    k_conv<<<512, 512, 0, stream>>>(x, wt2, scale, wsq, out);
}